// Round 4
// baseline (255.459 us; speedup 1.0000x reference)
//
#include <hip/hip_runtime.h>
#include <hip/hip_bf16.h>

// B=4, L=S=1024, D=1024, H=16, HD=64. Inputs fp32, output fp32, mask bool-ish
// (runtime-classified). History: R10 235us (proj 55us, FETCH ideal, MfmaUtil
// 17% — latency-bound). R11 dbuf+XOR-swizzle: conflicts 3.1M->0, dur flat.
// R12 counted-vmcnt 3-buf: 61us regression (load-wait ~0; sched-insensitive).
// R13 fp32-direct proj (delete 70MB convert traffic): proj 86us REGRESSION —
// NOT the reg-stage path: two gemm_core instantiations each allocated their
// own static __shared__ -> LDS 64KB -> 2 blocks/CU (vs 3). R14: hoist the
// shared buffers to kernel scope (single 32KB, passed by reference); rest of
// R13 unchanged. Expect proj ~58-62, LDS 32768, total ~225.

typedef __bf16 bf16;
typedef __bf16 bf16x8 __attribute__((ext_vector_type(8)));
typedef float floatx4 __attribute__((ext_vector_type(4)));

#define D_MODEL 1024
#define NHEAD   16
#define HDIM    64
#define BATCH   4
#define SEQ     1024
#define M_ROWS  (BATCH * SEQ)         // 4096
#define ACT_N   ((size_t)M_ROWS * D_MODEL)    // 4M
#define W_N     ((size_t)D_MODEL * D_MODEL)   // 1M
#define SC2     0.18033688011112042f  // 0.125 * log2(e)

#define GLD(gp, lp) __builtin_amdgcn_global_load_lds( \
    (__attribute__((address_space(1))) void*)(gp), \
    (__attribute__((address_space(3))) void*)(lp), 16, 0, 0)

__device__ __forceinline__ bf16x8 cvt8(const float4& f0, const float4& f1)
{
    bf16x8 o;
    o[0] = (bf16)f0.x; o[1] = (bf16)f0.y; o[2] = (bf16)f0.z; o[3] = (bf16)f0.w;
    o[4] = (bf16)f1.x; o[5] = (bf16)f1.y; o[6] = (bf16)f1.z; o[7] = (bf16)f1.w;
    return o;
}

// ---------------------------------------------------------------------------
// Weights-only convert + mask. Blocks 0..2047: fp32->bf16 of Wq,Wk,Wv,Wo
// (4x 1M elems) into contiguous bf16. Block 2048: classify mask dtype
// (int32/byte/bf16/fp32) and emit float bias 0 / -1e30.
// ---------------------------------------------------------------------------
__global__ __launch_bounds__(256)
void k_convert_w(const float* __restrict__ w0, const float* __restrict__ w1,
                 const float* __restrict__ w2, const float* __restrict__ w3,
                 bf16* __restrict__ dst,
                 const unsigned* __restrict__ m, float* __restrict__ mbias)
{
    if (blockIdx.x == 2048) {
        __shared__ unsigned viol[4];
        __shared__ int fmsh;
        if (threadIdx.x < 4) viol[threadIdx.x] = 0;
        __syncthreads();
        unsigned a = 0, b = 0, c = 0, d = 0;
        for (int i = threadIdx.x; i < 1024; i += 256) {
            unsigned v = m[i];
            if (v > 1u) a = 1;
            if (((v & 0xFFu) > 1u) || (((v >> 8) & 0xFFu) > 1u) ||
                (((v >> 16) & 0xFFu) > 1u) || (((v >> 24) & 0xFFu) > 1u)) b = 1;
            unsigned lo = v & 0xFFFFu, hi = v >> 16;
            if (!((lo == 0u || lo == 0x3F80u) && (hi == 0u || hi == 0x3F80u))) c = 1;
            if (lo != 0u) d = 1;
        }
        if (a) atomicOr(&viol[0], 1u);
        if (b) atomicOr(&viol[1], 1u);
        if (c) atomicOr(&viol[2], 1u);
        if (d) atomicOr(&viol[3], 1u);
        __syncthreads();
        if (threadIdx.x == 0) {
            int fm;
            if (!viol[0])      fm = 1;
            else if (!viol[1]) fm = 0;
            else if (!viol[2]) fm = viol[3] ? 2 : 3;
            else               fm = 0;
            fmsh = fm;
        }
        __syncthreads();
        const int fm = fmsh;
        for (int i = 0; i < 16; ++i) {
            int s = i * 256 + threadIdx.x;
            bool msk;
            if (fm == 1)      msk = ((const int*)m)[s] != 0;
            else if (fm == 2) msk = ((const unsigned short*)m)[s] != 0;
            else if (fm == 3) msk = ((const unsigned*)m)[s] != 0;
            else              msk = ((const unsigned char*)m)[s] != 0;
            mbias[s] = msk ? -1e30f : 0.f;
        }
        return;
    }

    size_t i = ((size_t)blockIdx.x * 256 + threadIdx.x) * 8;
    int j = (int)(i >> 20);
    const float* src = (j == 0) ? w0 : (j == 1) ? w1 : (j == 2) ? w2 : w3;
    size_t off = i & (((size_t)1 << 20) - 1);
    float4 f0 = ((const float4*)(src + off))[0];
    float4 f1 = ((const float4*)(src + off))[1];
    *(bf16x8*)(dst + i) = cvt8(f0, f1);
}

// ---------------------------------------------------------------------------
// GEMM core: C[m0..+128, n0..+128] = A@W^T + bias. BK=32, double-buffered
// R11 schedule (verified): stage k0+32 before compute(k0), one __syncthreads
// per step. Shared buffers are KERNEL-SCOPE and passed by reference — one
// 32KB allocation regardless of how many template instantiations the kernel
// touches (R13 bug: per-instantiation static __shared__ doubled LDS).
// Per-operand staging path:
//   bf16 (F32=false): global_load_lds, source address pre-swizzled (GLD LDS
//     dest must stay linear) — phys chunk (c&3) holds logical (c&3)^xr.
//   fp32 (F32=true): reg-staged — read LOGICAL chunk (c&3) from global
//     (coalesced 128B/row), cvt to bf16 after the MFMAs (mini-T14: HBM
//     latency hides under compute), ds_write_b128 to the SWIZZLED phys slot.
// Both paths produce identical LDS layout; fragment ds_read uses quad^xr.
// Swizzle xr(row)=(row>>1)&3 — verified R11: SQ_LDS_BANK_CONFLICT = 0.
// ---------------------------------------------------------------------------
typedef bf16 lds_tile_t[128 * 32];

template<bool F32>
__device__ __forceinline__ void stage_issue(const void* __restrict__ base,
                                            int r0, int kk,
                                            const int srow[2], const int schk[2],
                                            const int sx[2], int w,
                                            bf16* lds, float4 pre[2][2])
{
    #pragma unroll
    for (int ii = 0; ii < 2; ++ii) {
        if constexpr (F32) {
            const float* g = (const float*)base
                + (size_t)(r0 + srow[ii]) * D_MODEL + kk + schk[ii] * 8;
            pre[ii][0] = ((const float4*)g)[0];
            pre[ii][1] = ((const float4*)g)[1];
        } else {
            GLD((const bf16*)base + (size_t)(r0 + srow[ii]) * D_MODEL + kk + sx[ii] * 8,
                lds + (ii * 256 + w * 64) * 8);
        }
    }
}

template<bool F32>
__device__ __forceinline__ void stage_write(const int srow[2], const int sx[2],
                                            bf16* lds, const float4 pre[2][2])
{
    if constexpr (F32) {
        #pragma unroll
        for (int ii = 0; ii < 2; ++ii)
            *(bf16x8*)&lds[srow[ii] * 32 + sx[ii] * 8] = cvt8(pre[ii][0], pre[ii][1]);
    }
}

template<typename CT, bool AF32, bool WF32>
__device__ __forceinline__ void gemm_core(lds_tile_t* As, lds_tile_t* Bs,
                                          const void* __restrict__ Ap,
                                          const void* __restrict__ Wp,
                                          const float* __restrict__ bias,
                                          CT* __restrict__ C,
                                          int m0, int n0, bool rowBias)
{
    const int t    = threadIdx.x;
    const int lane = t & 63;
    const int w    = t >> 6;
    const int wm   = w >> 1, wn = w & 1;
    const int l15  = lane & 15;
    const int quad = lane >> 4;

    int srow[2], schk[2], sx[2];
    #pragma unroll
    for (int ii = 0; ii < 2; ++ii) {
        int c = ii * 256 + t;
        srow[ii] = c >> 2;
        schk[ii] = c & 3;
        sx[ii]   = schk[ii] ^ ((srow[ii] >> 1) & 3);
    }

    floatx4 acc[4][4] = {};
    float4 pa[2][2], pw[2][2];

    // prologue: stage tile 0 into buffer 0
    stage_issue<AF32>(Ap, m0, 0, srow, schk, sx, w, As[0], pa);
    stage_issue<WF32>(Wp, n0, 0, srow, schk, sx, w, Bs[0], pw);
    stage_write<AF32>(srow, sx, As[0], pa);
    stage_write<WF32>(srow, sx, Bs[0], pw);
    __syncthreads();

    int cur = 0;
    for (int k0 = 0; k0 < D_MODEL; k0 += 32) {
        const int nk = k0 + 32;
        if (nk < D_MODEL) {
            stage_issue<AF32>(Ap, m0, nk, srow, schk, sx, w, As[cur ^ 1], pa);
            stage_issue<WF32>(Wp, n0, nk, srow, schk, sx, w, Bs[cur ^ 1], pw);
        }

        bf16x8 af[4], bfr[4];
        #pragma unroll
        for (int i = 0; i < 4; ++i) {
            int r = wm * 64 + i * 16 + l15;
            af[i] = *(const bf16x8*)&As[cur][r * 32 + (quad ^ ((r >> 1) & 3)) * 8];
        }
        #pragma unroll
        for (int j = 0; j < 4; ++j) {
            int r = wn * 64 + j * 16 + l15;
            bfr[j] = *(const bf16x8*)&Bs[cur][r * 32 + (quad ^ ((r >> 1) & 3)) * 8];
        }

        #pragma unroll
        for (int i = 0; i < 4; ++i)
            #pragma unroll
            for (int j = 0; j < 4; ++j)
                acc[i][j] = __builtin_amdgcn_mfma_f32_16x16x32_bf16(
                    af[i], bfr[j], acc[i][j], 0, 0, 0);

        if (nk < D_MODEL) {
            stage_write<AF32>(srow, sx, As[cur ^ 1], pa);
            stage_write<WF32>(srow, sx, Bs[cur ^ 1], pw);
        }
        __syncthreads();
        cur ^= 1;
    }

    // epilogue: C/D layout col=lane&15, row=quad*4+r
    #pragma unroll
    for (int i = 0; i < 4; ++i) {
        int rowb = m0 + wm * 64 + i * 16 + quad * 4;
        float bvr[4];
        if (rowBias) {
            #pragma unroll
            for (int r = 0; r < 4; ++r) bvr[r] = bias[rowb + r];
        }
        #pragma unroll
        for (int j = 0; j < 4; ++j) {
            int col = n0 + wn * 64 + j * 16 + l15;
            float bc = rowBias ? 0.f : bias[col];
            #pragma unroll
            for (int r = 0; r < 4; ++r) {
                float val = acc[i][j][r] + (rowBias ? bvr[r] : bc);
                C[(size_t)(rowb + r) * D_MODEL + col] = (CT)val;
            }
        }
    }
}

// ---------------------------------------------------------------------------
// Fused projection GEMM, XCD-swizzled. 768 blocks; HW round-robins blockIdx
// across 8 XCDs (bid&7). Pair p = (z,m)-slice; its 8 n-blocks all carry the
// same bid&7 -> same XCD -> A-slice fetched once, W (2MB) stays L2-resident.
// p<32: Q-proj m=p (A=q fp32 reg-staged, W=Wq bf16 GLD). p<64: K-proj.
// p>=64: V-proj transposed per batch (Vt_b = Wv @ value_b^T + bv by row;
// A=Wv bf16 GLD, W=value fp32 reg-staged), batch=(p-64)>>3, m=(p-64)&7.
// ---------------------------------------------------------------------------
__global__ __launch_bounds__(256)
void k_gemm_proj(const float* __restrict__ qf, const float* __restrict__ kf,
                 const float* __restrict__ vf,
                 const bf16* __restrict__ cWq, const bf16* __restrict__ cWk,
                 const bf16* __restrict__ cWv,
                 const float* __restrict__ bq, const float* __restrict__ bk,
                 const float* __restrict__ bv,
                 bf16* __restrict__ qproj, bf16* __restrict__ kproj,
                 bf16* __restrict__ vt)
{
    __shared__ alignas(16) bf16 As[2][128 * 32];   // single 32KB for ALL
    __shared__ alignas(16) bf16 Bs[2][128 * 32];   // gemm_core instantiations

    const int bid = blockIdx.x;
    const int x = bid & 7;            // XCD
    const int j = bid >> 3;           // 0..95
    const int p = x * 12 + (j >> 3);  // pair 0..95
    const int n0 = (j & 7) * 128;
    if (p < 64) {
        int z = p >> 5, m0 = (p & 31) * 128;
        gemm_core<bf16, true, false>(As, Bs,
                                     z ? (const void*)kf : (const void*)qf,
                                     z ? (const void*)cWk : (const void*)cWq,
                                     z ? bk : bq, z ? kproj : qproj,
                                     m0, n0, false);
    } else {
        int pv = p - 64;
        int b = pv >> 3, m0 = (pv & 7) * 128;
        gemm_core<bf16, false, true>(As, Bs, cWv, vf + (size_t)b * W_N, bv,
                                     vt + (size_t)b * W_N, m0, n0, true);
    }
}

// O-projection, XCD-swizzled: 256 blocks, 32 m-pairs x 8 n. Both operands
// bf16 (ctx from attn, Wo pre-converted) -> pure GLD path.
__global__ __launch_bounds__(256)
void k_gemm_o(const bf16* __restrict__ A, const bf16* __restrict__ W,
              const float* __restrict__ bb, float* __restrict__ C)
{
    __shared__ alignas(16) bf16 As[2][128 * 32];
    __shared__ alignas(16) bf16 Bs[2][128 * 32];

    const int bid = blockIdx.x;
    const int x = bid & 7;
    const int j = bid >> 3;           // 0..31
    const int p = x * 4 + (j >> 3);   // m-pair 0..31
    const int n0 = (j & 7) * 128;
    gemm_core<float, false, false>(As, Bs, A, W, bb, C, p * 128, n0, false);
}

// ---------------------------------------------------------------------------
// Flash attention, fragment-ordered LDS (verified R11 version, unchanged).
// Grid (B*H, L/64) — bh on x so all 16 q-tiles of one (b,h) share an XCD.
// 256 thr (4 waves), wave = 16 q rows. No-max exp2 softmax; l via MFMA with
// ones-B-fragment. K/V double-buffered, prefetch before compute; Q staged
// through Past; mbias from L2-resident global. LDS 40KB -> 4 blocks/CU.
// ---------------------------------------------------------------------------
__global__ __launch_bounds__(256)
void k_attn(const bf16* __restrict__ qproj, const bf16* __restrict__ kproj,
            const bf16* __restrict__ vt, const float* __restrict__ mbias_g,
            bf16* __restrict__ ctx)
{
    __shared__ alignas(16) bf16 Kst[2][4096];  // [f=j*2+kk][lane]*8, frag order
    __shared__ alignas(16) bf16 Vst[2][4096];
    __shared__ alignas(16) bf16 Past[4096];    // per-wave 1024; also Q staging

    const int t    = threadIdx.x;
    const int lane = t & 63;
    const int w    = t >> 6;
    const int l15  = lane & 15;
    const int quad = lane >> 4;

    const int b  = blockIdx.x >> 4;
    const int h  = blockIdx.x & 15;
    const int q0 = blockIdx.y * 64;

    // stage Q into Past (each wave writes only its own w*1024 region)
    #pragma unroll
    for (int kk = 0; kk < 2; ++kk) {
        const bf16* gp = qproj + (size_t)(b * SEQ + q0 + w * 16 + l15) * D_MODEL
                       + h * HDIM + kk * 32 + quad * 8;
        GLD(gp, Past + (w * 2 + kk) * 512);
    }
    // stage K/V tile 0 into buffer 0
    #pragma unroll
    for (int i = 0; i < 2; ++i) {
        int f   = w * 2 + i;
        int row = (f >> 1) * 16 + l15;          // s-row (K) / d-row (Vt)
        int cb  = (f & 1) * 32 + quad * 8;
        GLD(kproj + (size_t)(b * SEQ + row) * D_MODEL + h * HDIM + cb,
            Kst[0] + f * 512);
        GLD(vt + (size_t)(b * 1024 + h * HDIM + row) * D_MODEL + cb,
            Vst[0] + f * 512);
    }
    __syncthreads();

    bf16x8 qf[2];
    #pragma unroll
    for (int kk = 0; kk < 2; ++kk)
        qf[kk] = *(const bf16x8*)&Past[(w * 2 + kk) * 512 + lane * 8];

    bf16x8 ones;
    #pragma unroll
    for (int e = 0; e < 8; ++e) ones[e] = (bf16)1.0f;

    floatx4 o[4] = {};
    floatx4 accl = {};

    const int pbase = w * 1024 + (l15 >> 3) * 128 + quad * 32 + (l15 & 7);
    const float* __restrict__ mbb = mbias_g + b * SEQ;

    int cur = 0;
    for (int s0 = 0; s0 < SEQ; s0 += 64) {
        // prefetch next K/V tile into the other buffer BEFORE compute
        if (s0 + 64 < SEQ) {
            #pragma unroll
            for (int i = 0; i < 2; ++i) {
                int f   = w * 2 + i;
                int row = (f >> 1) * 16 + l15;
                int cb  = (f & 1) * 32 + quad * 8;
                GLD(kproj + (size_t)(b * SEQ + s0 + 64 + row) * D_MODEL
                        + h * HDIM + cb,
                    Kst[cur ^ 1] + f * 512);
                GLD(vt + (size_t)(b * 1024 + h * HDIM + row) * D_MODEL
                        + s0 + 64 + cb,
                    Vst[cur ^ 1] + f * 512);
            }
        }

        floatx4 s_acc[4] = {};
        #pragma unroll
        for (int j = 0; j < 4; ++j)
            #pragma unroll
            for (int kk = 0; kk < 2; ++kk) {
                bf16x8 kf = *(const bf16x8*)&Kst[cur][(j * 2 + kk) * 512 + lane * 8];
                s_acc[j] = __builtin_amdgcn_mfma_f32_16x16x32_bf16(
                    qf[kk], kf, s_acc[j], 0, 0, 0);
            }

        #pragma unroll
        for (int j = 0; j < 4; ++j) {
            float mb = mbb[s0 + j * 16 + l15];
            #pragma unroll
            for (int r = 0; r < 4; ++r) {
                float p = __builtin_amdgcn_exp2f(fmaf(s_acc[j][r], SC2, mb));
                Past[pbase + (j >> 1) * 512 + (j & 1) * 256 + r * 8] = (bf16)p;
            }
        }
        __builtin_amdgcn_wave_barrier();

        bf16x8 pf[2];
        #pragma unroll
        for (int kk = 0; kk < 2; ++kk)
            pf[kk] = *(const bf16x8*)&Past[w * 1024 + kk * 512 + lane * 8];

        #pragma unroll
        for (int kk = 0; kk < 2; ++kk)
            accl = __builtin_amdgcn_mfma_f32_16x16x32_bf16(pf[kk], ones, accl,
                                                           0, 0, 0);
        #pragma unroll
        for (int j = 0; j < 4; ++j)
            #pragma unroll
            for (int kk = 0; kk < 2; ++kk) {
                bf16x8 vf = *(const bf16x8*)&Vst[cur][(j * 2 + kk) * 512 + lane * 8];
                o[j] = __builtin_amdgcn_mfma_f32_16x16x32_bf16(
                    pf[kk], vf, o[j], 0, 0, 0);
            }

        __syncthreads();   // next K/V tile ready; current buffers free
        cur ^= 1;
    }

    float inv[4];
    #pragma unroll
    for (int r = 0; r < 4; ++r) inv[r] = (accl[r] > 0.f) ? 1.f / accl[r] : 0.f;
    #pragma unroll
    for (int j = 0; j < 4; ++j)
        #pragma unroll
        for (int r = 0; r < 4; ++r) {
            int row = q0 + w * 16 + quad * 4 + r;
            int col = h * HDIM + j * 16 + l15;
            ctx[(size_t)(b * SEQ + row) * D_MODEL + col] = (bf16)(o[j][r] * inv[r]);
        }
}

// ---------------------------------------------------------------------------
extern "C" void kernel_launch(void* const* d_in, const int* in_sizes, int n_in,
                              void* d_out, int out_size, void* d_ws, size_t ws_size,
                              hipStream_t stream)
{
    // ws: [0,16K) mbias fp32 | [64K,+8MB) weights bf16 (Wq,Wk,Wv,Wo)
    //     | qproj 8MB | kproj 8MB | vt 8MB | ctx 8MB.   Total ~40.1MB.
    char* wsb = (char*)d_ws;
    float* mbias = (float*)wsb;
    bf16* cbase = (bf16*)(wsb + 65536);
    bf16 *cWq = cbase, *cWk = cWq + W_N, *cWv = cWk + W_N, *cWo = cWv + W_N;
    bf16* qproj = cWo + W_N;
    bf16* kproj = qproj + ACT_N;
    bf16* vt    = kproj + ACT_N;
    bf16* ctx   = vt + ACT_N;
    float* out  = (float*)d_out;

    k_convert_w<<<2049, 256, 0, stream>>>(
        (const float*)d_in[4], (const float*)d_in[6], (const float*)d_in[8],
        (const float*)d_in[10], cbase, (const unsigned*)d_in[3], mbias);

    k_gemm_proj<<<768, 256, 0, stream>>>(
        (const float*)d_in[0], (const float*)d_in[1], (const float*)d_in[2],
        cWq, cWk, cWv,
        (const float*)d_in[5], (const float*)d_in[7], (const float*)d_in[9],
        qproj, kproj, vt);
    k_attn<<<dim3(64, 16), 256, 0, stream>>>(qproj, kproj, vt, mbias, ctx);
    k_gemm_o<<<256, 256, 0, stream>>>(ctx, cWo, (const float*)d_in[11], out);
}

// Round 5
// 238.562 us; speedup vs baseline: 1.0708x; 1.0708x over previous
//
#include <hip/hip_runtime.h>
#include <hip/hip_bf16.h>

// B=4, L=S=1024, D=1024, H=16, HD=64. Inputs fp32, output fp32, mask bool-ish
// (runtime-classified). History: R10 235us (proj 55us, FETCH ideal, MfmaUtil
// 17%, latency-bound). R11 dbuf+XOR-swizzle: conflicts 3.1M->0, dur flat.
// R12 counted-vmcnt 3-buf: 61us (sched-insensitive). R13/R14 fp32-direct
// proj: 86us both — reg-staged fp32 path costs +30us intrinsically (+15MB
// fp32 bytes + vmcnt-serialized cvt/ds_write chain); REVERTED.
// R15: all variants shared grid=768=3 blocks/CU — the one resource never
// varied. LDS/VGPR allow 8+; latency-bound kernel is grid-starved. Halve
// BN: 128x64 tiles -> proj 1536 blocks (6/CU), o-proj 512 (2/CU). Same
// per-CU MFMA work/step, 2x independent chains. R11 sync structure,
// swizzle, GLD staging inherited unchanged.

typedef __bf16 bf16;
typedef __bf16 bf16x8 __attribute__((ext_vector_type(8)));
typedef float floatx4 __attribute__((ext_vector_type(4)));

#define D_MODEL 1024
#define NHEAD   16
#define HDIM    64
#define BATCH   4
#define SEQ     1024
#define M_ROWS  (BATCH * SEQ)         // 4096
#define ACT_N   ((size_t)M_ROWS * D_MODEL)    // 4M
#define W_N     ((size_t)D_MODEL * D_MODEL)   // 1M
#define SC2     0.18033688011112042f  // 0.125 * log2(e)

#define GLD(gp, lp) __builtin_amdgcn_global_load_lds( \
    (__attribute__((address_space(1))) void*)(gp), \
    (__attribute__((address_space(3))) void*)(lp), 16, 0, 0)

// ---------------------------------------------------------------------------
// Fused convert + mask (R10-verbatim). Blocks 0..8191: fp32->bf16 of
// q,k,v,Wq,Wk,Wv,Wo into one contiguous bf16 region (8 elems/thread).
// Block 8192: classify mask dtype and emit float bias 0 / -1e30.
// ---------------------------------------------------------------------------
__global__ __launch_bounds__(256)
void k_convert_all(const float* __restrict__ a0, const float* __restrict__ a1,
                   const float* __restrict__ a2,
                   const float* __restrict__ w0, const float* __restrict__ w1,
                   const float* __restrict__ w2, const float* __restrict__ w3,
                   bf16* __restrict__ dst,
                   const unsigned* __restrict__ m, float* __restrict__ mbias)
{
    if (blockIdx.x == 8192) {
        __shared__ unsigned viol[4];
        __shared__ int fmsh;
        if (threadIdx.x < 4) viol[threadIdx.x] = 0;
        __syncthreads();
        unsigned a = 0, b = 0, c = 0, d = 0;
        for (int i = threadIdx.x; i < 1024; i += 256) {
            unsigned v = m[i];
            if (v > 1u) a = 1;
            if (((v & 0xFFu) > 1u) || (((v >> 8) & 0xFFu) > 1u) ||
                (((v >> 16) & 0xFFu) > 1u) || (((v >> 24) & 0xFFu) > 1u)) b = 1;
            unsigned lo = v & 0xFFFFu, hi = v >> 16;
            if (!((lo == 0u || lo == 0x3F80u) && (hi == 0u || hi == 0x3F80u))) c = 1;
            if (lo != 0u) d = 1;
        }
        if (a) atomicOr(&viol[0], 1u);
        if (b) atomicOr(&viol[1], 1u);
        if (c) atomicOr(&viol[2], 1u);
        if (d) atomicOr(&viol[3], 1u);
        __syncthreads();
        if (threadIdx.x == 0) {
            int fm;
            if (!viol[0])      fm = 1;
            else if (!viol[1]) fm = 0;
            else if (!viol[2]) fm = viol[3] ? 2 : 3;
            else               fm = 0;
            fmsh = fm;
        }
        __syncthreads();
        const int fm = fmsh;
        for (int i = 0; i < 16; ++i) {
            int s = i * 256 + threadIdx.x;
            bool msk;
            if (fm == 1)      msk = ((const int*)m)[s] != 0;
            else if (fm == 2) msk = ((const unsigned short*)m)[s] != 0;
            else if (fm == 3) msk = ((const unsigned*)m)[s] != 0;
            else              msk = ((const unsigned char*)m)[s] != 0;
            mbias[s] = msk ? -1e30f : 0.f;
        }
        return;
    }

    size_t i = ((size_t)blockIdx.x * 256 + threadIdx.x) * 8;
    const float* src; size_t off;
    if (i < ((size_t)12 << 20)) {
        int z = (int)(i >> 22);
        src = (z == 0) ? a0 : (z == 1) ? a1 : a2;
        off = i & (((size_t)1 << 22) - 1);
    } else {
        size_t r = i - ((size_t)12 << 20);
        int j = (int)(r >> 20);
        src = (j == 0) ? w0 : (j == 1) ? w1 : (j == 2) ? w2 : w3;
        off = r & (((size_t)1 << 20) - 1);
    }
    float4 f0 = ((const float4*)(src + off))[0];
    float4 f1 = ((const float4*)(src + off))[1];
    bf16x8 o;
    o[0] = (bf16)f0.x; o[1] = (bf16)f0.y; o[2] = (bf16)f0.z; o[3] = (bf16)f0.w;
    o[4] = (bf16)f1.x; o[5] = (bf16)f1.y; o[6] = (bf16)f1.z; o[7] = (bf16)f1.w;
    *(bf16x8*)(dst + i) = o;
}

// ---------------------------------------------------------------------------
// GEMM core: C[m0..+128, n0..+64] = A@W^T + bias. BK=32, double-buffered
// R11 schedule (verified): stage k0+32 before compute(k0), one __syncthreads
// per step. All-bf16 GLD staging with source-side chunk-XOR swizzle (phys
// 16B chunk c&3 of row holds logical (c&3)^((row>>1)&3); fragment ds_read
// mirrors with quad^xr). Verified R11: SQ_LDS_BANK_CONFLICT = 0.
// 4 waves arranged 2(m)x2(n); wave tile 64x32: acc[4][2], 8 MFMA + 6
// ds_read_b128 per step. LDS 24KB (As 2x8KB, Bs 2x4KB).
// ---------------------------------------------------------------------------
template<typename CT>
__device__ __forceinline__ void gemm_core(const bf16* __restrict__ A,
                                          const bf16* __restrict__ W,
                                          const float* __restrict__ bias,
                                          CT* __restrict__ C,
                                          int m0, int n0, bool rowBias)
{
    __shared__ alignas(16) bf16 As[2][128 * 32];
    __shared__ alignas(16) bf16 Bs[2][64 * 32];

    const int t    = threadIdx.x;
    const int lane = t & 63;
    const int w    = t >> 6;
    const int wm   = w >> 1, wn = w & 1;
    const int l15  = lane & 15;
    const int quad = lane >> 4;

    floatx4 acc[4][2] = {};

    // staging index math (swizzled global source, linear LDS dest)
    int arow[2], asx[2];
    #pragma unroll
    for (int ii = 0; ii < 2; ++ii) {
        int c = ii * 256 + t;
        arow[ii] = c >> 2;
        asx[ii]  = (c & 3) ^ ((arow[ii] >> 1) & 3);
    }
    const int brow = t >> 2;
    const int bsx  = (t & 3) ^ ((brow >> 1) & 3);

    #define STAGE(k0s, buf) do {                                              \
        _Pragma("unroll")                                                     \
        for (int ii = 0; ii < 2; ++ii)                                        \
            GLD(A + (size_t)(m0 + arow[ii]) * D_MODEL + (k0s) + asx[ii] * 8,  \
                As[buf] + (ii * 256 + w * 64) * 8);                           \
        GLD(W + (size_t)(n0 + brow) * D_MODEL + (k0s) + bsx * 8,              \
            Bs[buf] + w * 512);                                               \
    } while (0)

    // prologue: stage tile 0 into buffer 0
    STAGE(0, 0);
    __syncthreads();

    int cur = 0;
    for (int k0 = 0; k0 < D_MODEL; k0 += 32) {
        const int nk = k0 + 32;
        if (nk < D_MODEL)
            STAGE(nk, cur ^ 1);

        bf16x8 af[4], bfr[2];
        #pragma unroll
        for (int i = 0; i < 4; ++i) {
            int r = wm * 64 + i * 16 + l15;
            af[i] = *(const bf16x8*)&As[cur][r * 32 + (quad ^ ((r >> 1) & 3)) * 8];
        }
        #pragma unroll
        for (int j = 0; j < 2; ++j) {
            int r = wn * 32 + j * 16 + l15;
            bfr[j] = *(const bf16x8*)&Bs[cur][r * 32 + (quad ^ ((r >> 1) & 3)) * 8];
        }

        #pragma unroll
        for (int i = 0; i < 4; ++i)
            #pragma unroll
            for (int j = 0; j < 2; ++j)
                acc[i][j] = __builtin_amdgcn_mfma_f32_16x16x32_bf16(
                    af[i], bfr[j], acc[i][j], 0, 0, 0);

        __syncthreads();
        cur ^= 1;
    }

    // epilogue: C/D layout col=lane&15, row=quad*4+r
    #pragma unroll
    for (int i = 0; i < 4; ++i) {
        int rowb = m0 + wm * 64 + i * 16 + quad * 4;
        float bvr[4];
        if (rowBias) {
            #pragma unroll
            for (int r = 0; r < 4; ++r) bvr[r] = bias[rowb + r];
        }
        #pragma unroll
        for (int j = 0; j < 2; ++j) {
            int col = n0 + wn * 32 + j * 16 + l15;
            float bc = rowBias ? 0.f : bias[col];
            #pragma unroll
            for (int r = 0; r < 4; ++r) {
                float val = acc[i][j][r] + (rowBias ? bvr[r] : bc);
                C[(size_t)(rowb + r) * D_MODEL + col] = (CT)val;
            }
        }
    }
    #undef STAGE
}

// ---------------------------------------------------------------------------
// Fused projection GEMM, XCD-swizzled. 1536 blocks (6/CU); HW round-robins
// blockIdx across 8 XCDs (bid&7). Pair p = (z,m)-slice; its 16 n-blocks all
// carry the same bid&7 -> same XCD -> A-slice fetched once, W (2MB) stays
// L2-resident. p<32: Q-proj m=p. p<64: K-proj m=p-32. p>=64: V-proj
// transposed per batch (Vt_b = Wv @ value_b^T + bv by row),
// batch=(p-64)>>3, m=(p-64)&7.
// ---------------------------------------------------------------------------
__global__ __launch_bounds__(256)
void k_gemm_proj(const bf16* __restrict__ cq, const bf16* __restrict__ ck,
                 const bf16* __restrict__ cv,
                 const bf16* __restrict__ cWq, const bf16* __restrict__ cWk,
                 const bf16* __restrict__ cWv,
                 const float* __restrict__ bq, const float* __restrict__ bk,
                 const float* __restrict__ bv,
                 bf16* __restrict__ qproj, bf16* __restrict__ kproj,
                 bf16* __restrict__ vt)
{
    const int bid = blockIdx.x;
    const int x = bid & 7;            // XCD
    const int j = bid >> 3;           // 0..191
    const int p = x * 12 + (j >> 4);  // pair 0..95
    const int n0 = (j & 15) * 64;
    if (p < 64) {
        int z = p >> 5, m0 = (p & 31) * 128;
        gemm_core<bf16>(z ? ck : cq, z ? cWk : cWq, z ? bk : bq,
                        z ? kproj : qproj, m0, n0, false);
    } else {
        int pv = p - 64;
        int b = pv >> 3, m0 = (pv & 7) * 128;
        gemm_core<bf16>(cWv, cv + (size_t)b * W_N, bv,
                        vt + (size_t)b * W_N, m0, n0, true);
    }
}

// O-projection, XCD-swizzled: 512 blocks (2/CU), 32 m-pairs x 16 n.
__global__ __launch_bounds__(256)
void k_gemm_o(const bf16* __restrict__ A, const bf16* __restrict__ W,
              const float* __restrict__ bb, float* __restrict__ C)
{
    const int bid = blockIdx.x;
    const int x = bid & 7;
    const int j = bid >> 3;           // 0..63
    const int p = x * 4 + (j >> 4);   // m-pair 0..31
    const int n0 = (j & 15) * 64;
    gemm_core<float>(A, W, bb, C, p * 128, n0, false);
}

// ---------------------------------------------------------------------------
// Flash attention, fragment-ordered LDS (verified R11 version, unchanged).
// Grid (B*H, L/64) — bh on x so all 16 q-tiles of one (b,h) share an XCD.
// 256 thr (4 waves), wave = 16 q rows. No-max exp2 softmax; l via MFMA with
// ones-B-fragment. K/V double-buffered, prefetch before compute; Q staged
// through Past; mbias from L2-resident global. LDS 40KB -> 4 blocks/CU.
// ---------------------------------------------------------------------------
__global__ __launch_bounds__(256)
void k_attn(const bf16* __restrict__ qproj, const bf16* __restrict__ kproj,
            const bf16* __restrict__ vt, const float* __restrict__ mbias_g,
            bf16* __restrict__ ctx)
{
    __shared__ alignas(16) bf16 Kst[2][4096];  // [f=j*2+kk][lane]*8, frag order
    __shared__ alignas(16) bf16 Vst[2][4096];
    __shared__ alignas(16) bf16 Past[4096];    // per-wave 1024; also Q staging

    const int t    = threadIdx.x;
    const int lane = t & 63;
    const int w    = t >> 6;
    const int l15  = lane & 15;
    const int quad = lane >> 4;

    const int b  = blockIdx.x >> 4;
    const int h  = blockIdx.x & 15;
    const int q0 = blockIdx.y * 64;

    // stage Q into Past (each wave writes only its own w*1024 region)
    #pragma unroll
    for (int kk = 0; kk < 2; ++kk) {
        const bf16* gp = qproj + (size_t)(b * SEQ + q0 + w * 16 + l15) * D_MODEL
                       + h * HDIM + kk * 32 + quad * 8;
        GLD(gp, Past + (w * 2 + kk) * 512);
    }
    // stage K/V tile 0 into buffer 0
    #pragma unroll
    for (int i = 0; i < 2; ++i) {
        int f   = w * 2 + i;
        int row = (f >> 1) * 16 + l15;          // s-row (K) / d-row (Vt)
        int cb  = (f & 1) * 32 + quad * 8;
        GLD(kproj + (size_t)(b * SEQ + row) * D_MODEL + h * HDIM + cb,
            Kst[0] + f * 512);
        GLD(vt + (size_t)(b * 1024 + h * HDIM + row) * D_MODEL + cb,
            Vst[0] + f * 512);
    }
    __syncthreads();

    bf16x8 qf[2];
    #pragma unroll
    for (int kk = 0; kk < 2; ++kk)
        qf[kk] = *(const bf16x8*)&Past[(w * 2 + kk) * 512 + lane * 8];

    bf16x8 ones;
    #pragma unroll
    for (int e = 0; e < 8; ++e) ones[e] = (bf16)1.0f;

    floatx4 o[4] = {};
    floatx4 accl = {};

    const int pbase = w * 1024 + (l15 >> 3) * 128 + quad * 32 + (l15 & 7);
    const float* __restrict__ mbb = mbias_g + b * SEQ;

    int cur = 0;
    for (int s0 = 0; s0 < SEQ; s0 += 64) {
        // prefetch next K/V tile into the other buffer BEFORE compute
        if (s0 + 64 < SEQ) {
            #pragma unroll
            for (int i = 0; i < 2; ++i) {
                int f   = w * 2 + i;
                int row = (f >> 1) * 16 + l15;
                int cb  = (f & 1) * 32 + quad * 8;
                GLD(kproj + (size_t)(b * SEQ + s0 + 64 + row) * D_MODEL
                        + h * HDIM + cb,
                    Kst[cur ^ 1] + f * 512);
                GLD(vt + (size_t)(b * 1024 + h * HDIM + row) * D_MODEL
                        + s0 + 64 + cb,
                    Vst[cur ^ 1] + f * 512);
            }
        }

        floatx4 s_acc[4] = {};
        #pragma unroll
        for (int j = 0; j < 4; ++j)
            #pragma unroll
            for (int kk = 0; kk < 2; ++kk) {
                bf16x8 kf = *(const bf16x8*)&Kst[cur][(j * 2 + kk) * 512 + lane * 8];
                s_acc[j] = __builtin_amdgcn_mfma_f32_16x16x32_bf16(
                    qf[kk], kf, s_acc[j], 0, 0, 0);
            }

        #pragma unroll
        for (int j = 0; j < 4; ++j) {
            float mb = mbb[s0 + j * 16 + l15];
            #pragma unroll
            for (int r = 0; r < 4; ++r) {
                float p = __builtin_amdgcn_exp2f(fmaf(s_acc[j][r], SC2, mb));
                Past[pbase + (j >> 1) * 512 + (j & 1) * 256 + r * 8] = (bf16)p;
            }
        }
        __builtin_amdgcn_wave_barrier();

        bf16x8 pf[2];
        #pragma unroll
        for (int kk = 0; kk < 2; ++kk)
            pf[kk] = *(const bf16x8*)&Past[w * 1024 + kk * 512 + lane * 8];

        #pragma unroll
        for (int kk = 0; kk < 2; ++kk)
            accl = __builtin_amdgcn_mfma_f32_16x16x32_bf16(pf[kk], ones, accl,
                                                           0, 0, 0);
        #pragma unroll
        for (int j = 0; j < 4; ++j)
            #pragma unroll
            for (int kk = 0; kk < 2; ++kk) {
                bf16x8 vf = *(const bf16x8*)&Vst[cur][(j * 2 + kk) * 512 + lane * 8];
                o[j] = __builtin_amdgcn_mfma_f32_16x16x32_bf16(
                    pf[kk], vf, o[j], 0, 0, 0);
            }

        __syncthreads();   // next K/V tile ready; current buffers free
        cur ^= 1;
    }

    float inv[4];
    #pragma unroll
    for (int r = 0; r < 4; ++r) inv[r] = (accl[r] > 0.f) ? 1.f / accl[r] : 0.f;
    #pragma unroll
    for (int j = 0; j < 4; ++j)
        #pragma unroll
        for (int r = 0; r < 4; ++r) {
            int row = q0 + w * 16 + quad * 4 + r;
            int col = h * HDIM + j * 16 + l15;
            ctx[(size_t)(b * SEQ + row) * D_MODEL + col] = (bf16)(o[j][r] * inv[r]);
        }
}

// ---------------------------------------------------------------------------
extern "C" void kernel_launch(void* const* d_in, const int* in_sizes, int n_in,
                              void* d_out, int out_size, void* d_ws, size_t ws_size,
                              hipStream_t stream)
{
    // ws: [0,16K) mbias fp32 | [64K,+32MB) converted bf16 (q,k,v,Wq,Wk,Wv,Wo)
    //     | qproj 8MB | kproj 8MB | vt 8MB | ctx 8MB.   Total ~64.1MB.
    char* wsb = (char*)d_ws;
    float* mbias = (float*)wsb;
    bf16* cbase = (bf16*)(wsb + 65536);
    bf16 *cq = cbase, *ck = cq + ACT_N, *cv = ck + ACT_N;
    bf16 *cWq = cv + ACT_N, *cWk = cWq + W_N, *cWv = cWk + W_N, *cWo = cWv + W_N;
    bf16* qproj = cWo + W_N;
    bf16* kproj = qproj + ACT_N;
    bf16* vt    = kproj + ACT_N;
    bf16* ctx   = vt + ACT_N;
    float* out  = (float*)d_out;

    k_convert_all<<<8193, 256, 0, stream>>>(
        (const float*)d_in[0], (const float*)d_in[1], (const float*)d_in[2],
        (const float*)d_in[4], (const float*)d_in[6], (const float*)d_in[8],
        (const float*)d_in[10], cbase, (const unsigned*)d_in[3], mbias);

    k_gemm_proj<<<1536, 256, 0, stream>>>(cq, ck, cv, cWq, cWk, cWv,
                                          (const float*)d_in[5],
                                          (const float*)d_in[7],
                                          (const float*)d_in[9],
                                          qproj, kproj, vt);
    k_attn<<<dim3(64, 16), 256, 0, stream>>>(qproj, kproj, vt, mbias, ctx);
    k_gemm_o<<<512, 256, 0, stream>>>(ctx, cWo, (const float*)d_in[11], out);
}

// Round 6
// 220.691 us; speedup vs baseline: 1.1575x; 1.0810x over previous
//
#include <hip/hip_runtime.h>
#include <hip/hip_bf16.h>

// B=4, L=S=1024, D=1024, H=16, HD=64. History: R10-R15: proj pinned at
// 55±6us across 2-phase/dbuf/counted-vmcnt/2x-occupancy/swizzle variants;
// MfmaUtil 17.4% invariant. Diagnosis (m233 match): 128-tile BK=32 pays a
// fixed ~1100cyc stage+drain+barrier chain per ~250cyc MFMA; no pipe >40%.
// R16: amortize — 256^2 tile, BK=64, 8 waves, ONE __syncthreads per 64-K
// tile (16 barriers vs 32), 4 quadrant-phases/tile (12 ds_read_b128 + 16
// MFMA each), dbuf 128KB dynamic LDS (1 blk/CU, m201 geometry), per-phase
// half-tile GLD prefetch into opposite buffer. 8-chunk XOR swizzle (R11
// involution generalized: phys chunk p of row r holds logical p^(r&7);
// pre-swizzled GLD source + mirrored ds_read; 64 lanes spread evenly over
// 8 bank-groups = conflict-free). proj 192 blocks, o-proj 64. Convert/attn
// unchanged (verified R10/R11).

typedef __bf16 bf16;
typedef __bf16 bf16x8 __attribute__((ext_vector_type(8)));
typedef float floatx4 __attribute__((ext_vector_type(4)));

#define D_MODEL 1024
#define NHEAD   16
#define HDIM    64
#define BATCH   4
#define SEQ     1024
#define M_ROWS  (BATCH * SEQ)         // 4096
#define ACT_N   ((size_t)M_ROWS * D_MODEL)    // 4M
#define W_N     ((size_t)D_MODEL * D_MODEL)   // 1M
#define SC2     0.18033688011112042f  // 0.125 * log2(e)

#define GLD(gp, lp) __builtin_amdgcn_global_load_lds( \
    (__attribute__((address_space(1))) void*)(gp), \
    (__attribute__((address_space(3))) void*)(lp), 16, 0, 0)

// ---------------------------------------------------------------------------
// Fused convert + mask (R10-verbatim, verified). Blocks 0..8191: fp32->bf16
// of q,k,v,Wq,Wk,Wv,Wo (8 elems/thread). Block 8192: classify mask dtype,
// emit float bias 0 / -1e30.
// ---------------------------------------------------------------------------
__global__ __launch_bounds__(256)
void k_convert_all(const float* __restrict__ a0, const float* __restrict__ a1,
                   const float* __restrict__ a2,
                   const float* __restrict__ w0, const float* __restrict__ w1,
                   const float* __restrict__ w2, const float* __restrict__ w3,
                   bf16* __restrict__ dst,
                   const unsigned* __restrict__ m, float* __restrict__ mbias)
{
    if (blockIdx.x == 8192) {
        __shared__ unsigned viol[4];
        __shared__ int fmsh;
        if (threadIdx.x < 4) viol[threadIdx.x] = 0;
        __syncthreads();
        unsigned a = 0, b = 0, c = 0, d = 0;
        for (int i = threadIdx.x; i < 1024; i += 256) {
            unsigned v = m[i];
            if (v > 1u) a = 1;
            if (((v & 0xFFu) > 1u) || (((v >> 8) & 0xFFu) > 1u) ||
                (((v >> 16) & 0xFFu) > 1u) || (((v >> 24) & 0xFFu) > 1u)) b = 1;
            unsigned lo = v & 0xFFFFu, hi = v >> 16;
            if (!((lo == 0u || lo == 0x3F80u) && (hi == 0u || hi == 0x3F80u))) c = 1;
            if (lo != 0u) d = 1;
        }
        if (a) atomicOr(&viol[0], 1u);
        if (b) atomicOr(&viol[1], 1u);
        if (c) atomicOr(&viol[2], 1u);
        if (d) atomicOr(&viol[3], 1u);
        __syncthreads();
        if (threadIdx.x == 0) {
            int fm;
            if (!viol[0])      fm = 1;
            else if (!viol[1]) fm = 0;
            else if (!viol[2]) fm = viol[3] ? 2 : 3;
            else               fm = 0;
            fmsh = fm;
        }
        __syncthreads();
        const int fm = fmsh;
        for (int i = 0; i < 16; ++i) {
            int s = i * 256 + threadIdx.x;
            bool msk;
            if (fm == 1)      msk = ((const int*)m)[s] != 0;
            else if (fm == 2) msk = ((const unsigned short*)m)[s] != 0;
            else if (fm == 3) msk = ((const unsigned*)m)[s] != 0;
            else              msk = ((const unsigned char*)m)[s] != 0;
            mbias[s] = msk ? -1e30f : 0.f;
        }
        return;
    }

    size_t i = ((size_t)blockIdx.x * 256 + threadIdx.x) * 8;
    const float* src; size_t off;
    if (i < ((size_t)12 << 20)) {
        int z = (int)(i >> 22);
        src = (z == 0) ? a0 : (z == 1) ? a1 : a2;
        off = i & (((size_t)1 << 22) - 1);
    } else {
        size_t r = i - ((size_t)12 << 20);
        int j = (int)(r >> 20);
        src = (j == 0) ? w0 : (j == 1) ? w1 : (j == 2) ? w2 : w3;
        off = r & (((size_t)1 << 20) - 1);
    }
    float4 f0 = ((const float4*)(src + off))[0];
    float4 f1 = ((const float4*)(src + off))[1];
    bf16x8 o;
    o[0] = (bf16)f0.x; o[1] = (bf16)f0.y; o[2] = (bf16)f0.z; o[3] = (bf16)f0.w;
    o[4] = (bf16)f1.x; o[5] = (bf16)f1.y; o[6] = (bf16)f1.z; o[7] = (bf16)f1.w;
    *(bf16x8*)(dst + i) = o;
}

// ---------------------------------------------------------------------------
// 256^2 / BK=64 / 8-wave GEMM core. C[m0..+256, n0..+256] = A@W^T + bias.
// Waves 2(M)x4(N); per-wave output 128x64 -> acc[8][4] f32x4 (128 VGPR).
// K: 16 tiles of 64. Per tile: 4 quadrant-phases (mq,nq); each phase:
//   {stage half-tile #ph of tile t+1 (2 GLD/thread) -> opposite buffer;
//    12 ds_read_b128 frags of quadrant; 16 MFMA}.
// ONE __syncthreads per tile boundary: drains vmcnt (t+1 staged, last half
// issued ~1 phase earlier) + aligns waves; buffer parity (t vs t+1) makes
// writes race-free vs reads. LDS: A 2x[256][64] + B 2x[256][64] = 128KB.
// Swizzle: phys 16B chunk p of row r holds logical chunk p^(r&7); staging
// pre-swizzles the GLOBAL source (GLD LDS dest linear); frag reads use
// chunk (kk*4+quad)^(l15&7). Even 8-lane/bank-group spread = conflict-free.
// ---------------------------------------------------------------------------
template<typename CT>
__device__ __forceinline__ void gemm8_core(const bf16* __restrict__ A,
                                           const bf16* __restrict__ W,
                                           const float* __restrict__ bias,
                                           CT* __restrict__ C,
                                           int m0, int n0, bool rowBias,
                                           bf16* __restrict__ As0,
                                           bf16* __restrict__ Bs0)
{
    const int t    = threadIdx.x;     // 0..511
    const int lane = t & 63;
    const int w    = t >> 6;          // 0..7
    const int wm   = w >> 2;          // 0..1
    const int wn   = w & 3;           // 0..3
    const int l15  = lane & 15;
    const int quad = lane >> 4;
    const int lx   = l15 & 7;         // read-side swizzle key (rows %16 == l15)

    floatx4 acc[8][4] = {};

    // staging geometry: half-tile = 128 rows x 64 cols = 16KB = 1024 x 16B;
    // chunk i = j*512 + t (j=0,1): row-in-half = i>>3, phys chunk = i&7,
    // logical (global) chunk = (i&7) ^ ((i>>3)&7).
    int srow[2], schk[2], ldso[2];
    #pragma unroll
    for (int j = 0; j < 2; ++j) {
        int i = j * 512 + t;
        srow[j] = i >> 3;
        schk[j] = (i & 7) ^ (srow[j] & 7);
        ldso[j] = (j * 512 + w * 64) * 8;   // wave-uniform elem offset in half
    }

    // stage half h (0/1) of the tile at k0 for operand src (row base rb)
    // into buffer buf of dst (As0 or Bs0).
    #define STAGE_HALF(src, rb, k0s, h, dstbuf) do {                          \
        _Pragma("unroll")                                                     \
        for (int j = 0; j < 2; ++j)                                           \
            GLD((src) + (size_t)((rb) + (h) * 128 + srow[j]) * D_MODEL        \
                    + (k0s) + schk[j] * 8,                                    \
                (dstbuf) + (h) * 8192 + ldso[j]);                             \
    } while (0)

    // prologue: tile 0 -> buffer 0
    STAGE_HALF(A, m0, 0, 0, As0);
    STAGE_HALF(A, m0, 0, 1, As0);
    STAGE_HALF(W, n0, 0, 0, Bs0);
    STAGE_HALF(W, n0, 0, 1, Bs0);
    __syncthreads();

    for (int kt = 0; kt < 16; ++kt) {
        const int nk = (kt + 1) * 64;
        const bf16* __restrict__ Ab = As0 + (kt & 1) * 16384;
        const bf16* __restrict__ Bb = Bs0 + (kt & 1) * 16384;
        bf16* __restrict__ An = As0 + ((kt + 1) & 1) * 16384;
        bf16* __restrict__ Bn = Bs0 + ((kt + 1) & 1) * 16384;

        #pragma unroll
        for (int ph = 0; ph < 4; ++ph) {
            const int mq = ph >> 1, nq = ph & 1;

            if (nk < D_MODEL) {       // stage half #ph of tile kt+1
                if (ph == 0)      STAGE_HALF(A, m0, nk, 0, An);
                else if (ph == 1) STAGE_HALF(A, m0, nk, 1, An);
                else if (ph == 2) STAGE_HALF(W, n0, nk, 0, Bn);
                else              STAGE_HALF(W, n0, nk, 1, Bn);
            }

            bf16x8 af[4][2], bfr[2][2];
            #pragma unroll
            for (int ii = 0; ii < 4; ++ii) {
                int row = wm * 128 + mq * 64 + ii * 16 + l15;
                #pragma unroll
                for (int kk = 0; kk < 2; ++kk)
                    af[ii][kk] = *(const bf16x8*)
                        &Ab[row * 64 + (((kk * 4 + quad) ^ lx)) * 8];
            }
            #pragma unroll
            for (int jj = 0; jj < 2; ++jj) {
                int row = wn * 64 + nq * 32 + jj * 16 + l15;
                #pragma unroll
                for (int kk = 0; kk < 2; ++kk)
                    bfr[jj][kk] = *(const bf16x8*)
                        &Bb[row * 64 + (((kk * 4 + quad) ^ lx)) * 8];
            }

            #pragma unroll
            for (int ii = 0; ii < 4; ++ii)
                #pragma unroll
                for (int jj = 0; jj < 2; ++jj)
                    #pragma unroll
                    for (int kk = 0; kk < 2; ++kk)
                        acc[mq * 4 + ii][nq * 2 + jj] =
                            __builtin_amdgcn_mfma_f32_16x16x32_bf16(
                                af[ii][kk], bfr[jj][kk],
                                acc[mq * 4 + ii][nq * 2 + jj], 0, 0, 0);
        }
        __syncthreads();   // tile t+1 landed; buffers swap
    }

    // epilogue: C/D layout col=lane&15, row=quad*4+r (verified convention)
    #pragma unroll
    for (int i = 0; i < 8; ++i) {
        int rowb = m0 + wm * 128 + i * 16 + quad * 4;
        float bvr[4];
        if (rowBias) {
            #pragma unroll
            for (int r = 0; r < 4; ++r) bvr[r] = bias[rowb + r];
        }
        #pragma unroll
        for (int jf = 0; jf < 4; ++jf) {
            int col = n0 + wn * 64 + jf * 16 + l15;
            float bc = rowBias ? 0.f : bias[col];
            #pragma unroll
            for (int r = 0; r < 4; ++r) {
                float val = acc[i][jf][r] + (rowBias ? bvr[r] : bc);
                C[(size_t)(rowb + r) * D_MODEL + col] = (CT)val;
            }
        }
    }
    #undef STAGE_HALF
}

// ---------------------------------------------------------------------------
// Fused projection GEMM, 192 blocks x 512 thr, XCD-chunked: tid = (bid&7)*24
// + bid>>3 so each XCD owns a contiguous slice of tiles (A-rows + W stay
// L2-local). tid<64: Q (m=tid>>2, n=tid&3); <128: K; else V per batch
// (Vt_b = Wv @ value_b^T + bv by row): b=(tid-128)>>4, m=((tid-128)>>2)&3.
// ---------------------------------------------------------------------------
__global__ __launch_bounds__(512, 2)
void k_gemm_proj(const bf16* __restrict__ cq, const bf16* __restrict__ ck,
                 const bf16* __restrict__ cv,
                 const bf16* __restrict__ cWq, const bf16* __restrict__ cWk,
                 const bf16* __restrict__ cWv,
                 const float* __restrict__ bq, const float* __restrict__ bk,
                 const float* __restrict__ bv,
                 bf16* __restrict__ qproj, bf16* __restrict__ kproj,
                 bf16* __restrict__ vt)
{
    extern __shared__ __align__(16) bf16 smem[];
    bf16* As0 = smem;            // 2 x 16384 elems
    bf16* Bs0 = smem + 32768;    // 2 x 16384 elems

    const int bid = blockIdx.x;
    const int tid = (bid & 7) * 24 + (bid >> 3);   // 0..191
    if (tid < 64) {
        gemm8_core<bf16>(cq, cWq, bq, qproj,
                         (tid >> 2) * 256, (tid & 3) * 256, false, As0, Bs0);
    } else if (tid < 128) {
        int u = tid - 64;
        gemm8_core<bf16>(ck, cWk, bk, kproj,
                         (u >> 2) * 256, (u & 3) * 256, false, As0, Bs0);
    } else {
        int v = tid - 128;
        int b = v >> 4, m = (v >> 2) & 3, n = v & 3;
        gemm8_core<bf16>(cWv, cv + (size_t)b * W_N, bv,
                         vt + (size_t)b * W_N, m * 256, n * 256, true,
                         As0, Bs0);
    }
}

// O-projection: 64 blocks x 512 thr (M=4096 x N=1024 in 256^2 tiles).
__global__ __launch_bounds__(512, 2)
void k_gemm_o(const bf16* __restrict__ A, const bf16* __restrict__ W,
              const float* __restrict__ bb, float* __restrict__ C)
{
    extern __shared__ __align__(16) bf16 smem[];
    bf16* As0 = smem;
    bf16* Bs0 = smem + 32768;

    const int bid = blockIdx.x;
    const int tid = (bid & 7) * 8 + (bid >> 3);    // 0..63
    gemm8_core<float>(A, W, bb, C, (tid >> 2) * 256, (tid & 3) * 256, false,
                      As0, Bs0);
}

// ---------------------------------------------------------------------------
// Flash attention, fragment-ordered LDS (verified R11 version, unchanged).
// ---------------------------------------------------------------------------
__global__ __launch_bounds__(256)
void k_attn(const bf16* __restrict__ qproj, const bf16* __restrict__ kproj,
            const bf16* __restrict__ vt, const float* __restrict__ mbias_g,
            bf16* __restrict__ ctx)
{
    __shared__ alignas(16) bf16 Kst[2][4096];  // [f=j*2+kk][lane]*8, frag order
    __shared__ alignas(16) bf16 Vst[2][4096];
    __shared__ alignas(16) bf16 Past[4096];    // per-wave 1024; also Q staging

    const int t    = threadIdx.x;
    const int lane = t & 63;
    const int w    = t >> 6;
    const int l15  = lane & 15;
    const int quad = lane >> 4;

    const int b  = blockIdx.x >> 4;
    const int h  = blockIdx.x & 15;
    const int q0 = blockIdx.y * 64;

    // stage Q into Past (each wave writes only its own w*1024 region)
    #pragma unroll
    for (int kk = 0; kk < 2; ++kk) {
        const bf16* gp = qproj + (size_t)(b * SEQ + q0 + w * 16 + l15) * D_MODEL
                       + h * HDIM + kk * 32 + quad * 8;
        GLD(gp, Past + (w * 2 + kk) * 512);
    }
    // stage K/V tile 0 into buffer 0
    #pragma unroll
    for (int i = 0; i < 2; ++i) {
        int f   = w * 2 + i;
        int row = (f >> 1) * 16 + l15;          // s-row (K) / d-row (Vt)
        int cb  = (f & 1) * 32 + quad * 8;
        GLD(kproj + (size_t)(b * SEQ + row) * D_MODEL + h * HDIM + cb,
            Kst[0] + f * 512);
        GLD(vt + (size_t)(b * 1024 + h * HDIM + row) * D_MODEL + cb,
            Vst[0] + f * 512);
    }
    __syncthreads();

    bf16x8 qf[2];
    #pragma unroll
    for (int kk = 0; kk < 2; ++kk)
        qf[kk] = *(const bf16x8*)&Past[(w * 2 + kk) * 512 + lane * 8];

    bf16x8 ones;
    #pragma unroll
    for (int e = 0; e < 8; ++e) ones[e] = (bf16)1.0f;

    floatx4 o[4] = {};
    floatx4 accl = {};

    const int pbase = w * 1024 + (l15 >> 3) * 128 + quad * 32 + (l15 & 7);
    const float* __restrict__ mbb = mbias_g + b * SEQ;

    int cur = 0;
    for (int s0 = 0; s0 < SEQ; s0 += 64) {
        // prefetch next K/V tile into the other buffer BEFORE compute
        if (s0 + 64 < SEQ) {
            #pragma unroll
            for (int i = 0; i < 2; ++i) {
                int f   = w * 2 + i;
                int row = (f >> 1) * 16 + l15;
                int cb  = (f & 1) * 32 + quad * 8;
                GLD(kproj + (size_t)(b * SEQ + s0 + 64 + row) * D_MODEL
                        + h * HDIM + cb,
                    Kst[cur ^ 1] + f * 512);
                GLD(vt + (size_t)(b * 1024 + h * HDIM + row) * D_MODEL
                        + s0 + 64 + cb,
                    Vst[cur ^ 1] + f * 512);
            }
        }

        floatx4 s_acc[4] = {};
        #pragma unroll
        for (int j = 0; j < 4; ++j)
            #pragma unroll
            for (int kk = 0; kk < 2; ++kk) {
                bf16x8 kf = *(const bf16x8*)&Kst[cur][(j * 2 + kk) * 512 + lane * 8];
                s_acc[j] = __builtin_amdgcn_mfma_f32_16x16x32_bf16(
                    qf[kk], kf, s_acc[j], 0, 0, 0);
            }

        #pragma unroll
        for (int j = 0; j < 4; ++j) {
            float mb = mbb[s0 + j * 16 + l15];
            #pragma unroll
            for (int r = 0; r < 4; ++r) {
                float p = __builtin_amdgcn_exp2f(fmaf(s_acc[j][r], SC2, mb));
                Past[pbase + (j >> 1) * 512 + (j & 1) * 256 + r * 8] = (bf16)p;
            }
        }
        __builtin_amdgcn_wave_barrier();

        bf16x8 pf[2];
        #pragma unroll
        for (int kk = 0; kk < 2; ++kk)
            pf[kk] = *(const bf16x8*)&Past[w * 1024 + kk * 512 + lane * 8];

        #pragma unroll
        for (int kk = 0; kk < 2; ++kk)
            accl = __builtin_amdgcn_mfma_f32_16x16x32_bf16(pf[kk], ones, accl,
                                                           0, 0, 0);
        #pragma unroll
        for (int j = 0; j < 4; ++j)
            #pragma unroll
            for (int kk = 0; kk < 2; ++kk) {
                bf16x8 vf = *(const bf16x8*)&Vst[cur][(j * 2 + kk) * 512 + lane * 8];
                o[j] = __builtin_amdgcn_mfma_f32_16x16x32_bf16(
                    pf[kk], vf, o[j], 0, 0, 0);
            }

        __syncthreads();   // next K/V tile ready; current buffers free
        cur ^= 1;
    }

    float inv[4];
    #pragma unroll
    for (int r = 0; r < 4; ++r) inv[r] = (accl[r] > 0.f) ? 1.f / accl[r] : 0.f;
    #pragma unroll
    for (int j = 0; j < 4; ++j)
        #pragma unroll
        for (int r = 0; r < 4; ++r) {
            int row = q0 + w * 16 + quad * 4 + r;
            int col = h * HDIM + j * 16 + l15;
            ctx[(size_t)(b * SEQ + row) * D_MODEL + col] = (bf16)(o[j][r] * inv[r]);
        }
}

// ---------------------------------------------------------------------------
extern "C" void kernel_launch(void* const* d_in, const int* in_sizes, int n_in,
                              void* d_out, int out_size, void* d_ws, size_t ws_size,
                              hipStream_t stream)
{
    // ws: [0,16K) mbias fp32 | [64K,+32MB) converted bf16 (q,k,v,Wq,Wk,Wv,Wo)
    //     | qproj 8MB | kproj 8MB | vt 8MB | ctx 8MB.   Total ~64.1MB.
    char* wsb = (char*)d_ws;
    float* mbias = (float*)wsb;
    bf16* cbase = (bf16*)(wsb + 65536);
    bf16 *cq = cbase, *ck = cq + ACT_N, *cv = ck + ACT_N;
    bf16 *cWq = cv + ACT_N, *cWk = cWq + W_N, *cWv = cWk + W_N, *cWo = cWv + W_N;
    bf16* qproj = cWo + W_N;
    bf16* kproj = qproj + ACT_N;
    bf16* vt    = kproj + ACT_N;
    bf16* ctx   = vt + ACT_N;
    float* out  = (float*)d_out;

    // allow 128KB dynamic LDS on the 8-wave GEMMs (host-side, capture-safe)
    static bool attrset = false;
    if (!attrset) {
        hipFuncSetAttribute((const void*)k_gemm_proj,
                            hipFuncAttributeMaxDynamicSharedMemorySize, 131072);
        hipFuncSetAttribute((const void*)k_gemm_o,
                            hipFuncAttributeMaxDynamicSharedMemorySize, 131072);
        attrset = true;
    }

    k_convert_all<<<8193, 256, 0, stream>>>(
        (const float*)d_in[0], (const float*)d_in[1], (const float*)d_in[2],
        (const float*)d_in[4], (const float*)d_in[6], (const float*)d_in[8],
        (const float*)d_in[10], cbase, (const unsigned*)d_in[3], mbias);

    k_gemm_proj<<<192, 512, 131072, stream>>>(cq, ck, cv, cWq, cWk, cWv,
                                              (const float*)d_in[5],
                                              (const float*)d_in[7],
                                              (const float*)d_in[9],
                                              qproj, kproj, vt);
    k_attn<<<dim3(64, 16), 256, 0, stream>>>(qproj, kproj, vt, mbias, ctx);
    k_gemm_o<<<64, 512, 131072, stream>>>(ctx, cWo, (const float*)d_in[11], out);
}

// Round 7
// 216.217 us; speedup vs baseline: 1.1815x; 1.0207x over previous
//
#include <hip/hip_runtime.h>
#include <hip/hip_bf16.h>

// B=4, L=S=1024, D=1024, H=16, HD=64. History: R10-R15 proj pinned ~55us
// (latency/barrier-bound, schedule-insensitive). R16: 256^2/BK=64/8-wave
// 4-phase proj+o-proj -> total 238.6->220.7us; proj left top-5. New top:
// attn 52.6us (MfmaUtil 13.7, conflicts 2.1M from P-store: bank=(q*4+e/2),
// sq*256B & q-bit3 bank-dead -> 4-way). R17: (1) attn QBLK=128 (wave=32 q
// rows, 2 groups): 36 MFMA/barrier, kf/vf reads+staging shared across
// groups, barriers per work halved; (2) Past padded strides sq*400B,
// qhi*160B (400/4=4, 160/4=8 mod 32) -> all-32-bank spread, worst 2-way
// (free); (3) o-proj NT=128 template -> 128 blocks (was 64 = 1/4 chip).

typedef __bf16 bf16;
typedef __bf16 bf16x8 __attribute__((ext_vector_type(8)));
typedef float floatx4 __attribute__((ext_vector_type(4)));

#define D_MODEL 1024
#define NHEAD   16
#define HDIM    64
#define BATCH   4
#define SEQ     1024
#define M_ROWS  (BATCH * SEQ)         // 4096
#define ACT_N   ((size_t)M_ROWS * D_MODEL)    // 4M
#define W_N     ((size_t)D_MODEL * D_MODEL)   // 1M
#define SC2     0.18033688011112042f  // 0.125 * log2(e)

#define GLD(gp, lp) __builtin_amdgcn_global_load_lds( \
    (__attribute__((address_space(1))) void*)(gp), \
    (__attribute__((address_space(3))) void*)(lp), 16, 0, 0)

// ---------------------------------------------------------------------------
// Fused convert + mask (R10-verbatim, verified).
// ---------------------------------------------------------------------------
__global__ __launch_bounds__(256)
void k_convert_all(const float* __restrict__ a0, const float* __restrict__ a1,
                   const float* __restrict__ a2,
                   const float* __restrict__ w0, const float* __restrict__ w1,
                   const float* __restrict__ w2, const float* __restrict__ w3,
                   bf16* __restrict__ dst,
                   const unsigned* __restrict__ m, float* __restrict__ mbias)
{
    if (blockIdx.x == 8192) {
        __shared__ unsigned viol[4];
        __shared__ int fmsh;
        if (threadIdx.x < 4) viol[threadIdx.x] = 0;
        __syncthreads();
        unsigned a = 0, b = 0, c = 0, d = 0;
        for (int i = threadIdx.x; i < 1024; i += 256) {
            unsigned v = m[i];
            if (v > 1u) a = 1;
            if (((v & 0xFFu) > 1u) || (((v >> 8) & 0xFFu) > 1u) ||
                (((v >> 16) & 0xFFu) > 1u) || (((v >> 24) & 0xFFu) > 1u)) b = 1;
            unsigned lo = v & 0xFFFFu, hi = v >> 16;
            if (!((lo == 0u || lo == 0x3F80u) && (hi == 0u || hi == 0x3F80u))) c = 1;
            if (lo != 0u) d = 1;
        }
        if (a) atomicOr(&viol[0], 1u);
        if (b) atomicOr(&viol[1], 1u);
        if (c) atomicOr(&viol[2], 1u);
        if (d) atomicOr(&viol[3], 1u);
        __syncthreads();
        if (threadIdx.x == 0) {
            int fm;
            if (!viol[0])      fm = 1;
            else if (!viol[1]) fm = 0;
            else if (!viol[2]) fm = viol[3] ? 2 : 3;
            else               fm = 0;
            fmsh = fm;
        }
        __syncthreads();
        const int fm = fmsh;
        for (int i = 0; i < 16; ++i) {
            int s = i * 256 + threadIdx.x;
            bool msk;
            if (fm == 1)      msk = ((const int*)m)[s] != 0;
            else if (fm == 2) msk = ((const unsigned short*)m)[s] != 0;
            else if (fm == 3) msk = ((const unsigned*)m)[s] != 0;
            else              msk = ((const unsigned char*)m)[s] != 0;
            mbias[s] = msk ? -1e30f : 0.f;
        }
        return;
    }

    size_t i = ((size_t)blockIdx.x * 256 + threadIdx.x) * 8;
    const float* src; size_t off;
    if (i < ((size_t)12 << 20)) {
        int z = (int)(i >> 22);
        src = (z == 0) ? a0 : (z == 1) ? a1 : a2;
        off = i & (((size_t)1 << 22) - 1);
    } else {
        size_t r = i - ((size_t)12 << 20);
        int j = (int)(r >> 20);
        src = (j == 0) ? w0 : (j == 1) ? w1 : (j == 2) ? w2 : w3;
        off = r & (((size_t)1 << 20) - 1);
    }
    float4 f0 = ((const float4*)(src + off))[0];
    float4 f1 = ((const float4*)(src + off))[1];
    bf16x8 o;
    o[0] = (bf16)f0.x; o[1] = (bf16)f0.y; o[2] = (bf16)f0.z; o[3] = (bf16)f0.w;
    o[4] = (bf16)f1.x; o[5] = (bf16)f1.y; o[6] = (bf16)f1.z; o[7] = (bf16)f1.w;
    *(bf16x8*)(dst + i) = o;
}

// ---------------------------------------------------------------------------
// 256xNT / BK=64 / 8-wave GEMM core (R16-verified at NT=256).
// C[m0..+256, n0..+NT] = A@W^T + bias. Waves 2(M)x4(N); per-wave output
// 128 x NT/4 -> acc[8][NT/64]. 16 K-tiles of 64; 4 quadrant-phases per tile,
// each: {stage one half-tile of t+1 -> opposite buffer; ds_read quadrant
// frags; MFMA}. ONE __syncthreads per tile. Swizzle: phys 16B chunk p of
// row r holds logical p^(r&7); pre-swizzled GLD source, mirrored ds_read.
// ---------------------------------------------------------------------------
template<typename CT, int NT>
__device__ __forceinline__ void gemm8_core(const bf16* __restrict__ A,
                                           const bf16* __restrict__ W,
                                           const float* __restrict__ bias,
                                           CT* __restrict__ C,
                                           int m0, int n0, bool rowBias,
                                           bf16* __restrict__ As0,
                                           bf16* __restrict__ Bs0)
{
    const int t    = threadIdx.x;     // 0..511
    const int lane = t & 63;
    const int w    = t >> 6;          // 0..7
    const int wm   = w >> 2;          // 0..1
    const int wn   = w & 3;           // 0..3
    const int l15  = lane & 15;
    const int quad = lane >> 4;
    const int lx   = l15 & 7;

    constexpr int NJ = NT / 128;      // B jj-count per quadrant (2 or 1)
    constexpr int BSTRIDE = NT * 64;  // elems per B buffer

    floatx4 acc[8][NT / 64] = {};

    int srow[2], schk[2], ldso[2];
    #pragma unroll
    for (int j = 0; j < 2; ++j) {
        int i = j * 512 + t;
        srow[j] = i >> 3;
        schk[j] = (i & 7) ^ (srow[j] & 7);
        ldso[j] = (j * 512 + w * 64) * 8;
    }

    #define STAGE_HALF(src, rb, k0s, h, dstbuf) do {                          \
        _Pragma("unroll")                                                     \
        for (int j = 0; j < 2; ++j)                                           \
            GLD((src) + (size_t)((rb) + (h) * 128 + srow[j]) * D_MODEL        \
                    + (k0s) + schk[j] * 8,                                    \
                (dstbuf) + (h) * 8192 + ldso[j]);                             \
    } while (0)

    // prologue: tile 0 -> buffer 0
    STAGE_HALF(A, m0, 0, 0, As0);
    STAGE_HALF(A, m0, 0, 1, As0);
    STAGE_HALF(W, n0, 0, 0, Bs0);
    if constexpr (NT == 256) STAGE_HALF(W, n0, 0, 1, Bs0);
    __syncthreads();

    for (int kt = 0; kt < 16; ++kt) {
        const int nk = (kt + 1) * 64;
        const bf16* __restrict__ Ab = As0 + (kt & 1) * 16384;
        const bf16* __restrict__ Bb = Bs0 + (kt & 1) * BSTRIDE;
        bf16* __restrict__ An = As0 + ((kt + 1) & 1) * 16384;
        bf16* __restrict__ Bn = Bs0 + ((kt + 1) & 1) * BSTRIDE;

        #pragma unroll
        for (int ph = 0; ph < 4; ++ph) {
            const int mq = ph >> 1, nq = ph & 1;

            if (nk < D_MODEL) {       // stage one half of tile kt+1
                if constexpr (NT == 256) {
                    if (ph == 0)      STAGE_HALF(A, m0, nk, 0, An);
                    else if (ph == 1) STAGE_HALF(A, m0, nk, 1, An);
                    else if (ph == 2) STAGE_HALF(W, n0, nk, 0, Bn);
                    else              STAGE_HALF(W, n0, nk, 1, Bn);
                } else {
                    if (ph == 0)      STAGE_HALF(A, m0, nk, 0, An);
                    else if (ph == 1) STAGE_HALF(A, m0, nk, 1, An);
                    else if (ph == 2) STAGE_HALF(W, n0, nk, 0, Bn);
                }
            }

            bf16x8 af[4][2], bfr[NJ][2];
            #pragma unroll
            for (int ii = 0; ii < 4; ++ii) {
                int row = wm * 128 + mq * 64 + ii * 16 + l15;
                #pragma unroll
                for (int kk = 0; kk < 2; ++kk)
                    af[ii][kk] = *(const bf16x8*)
                        &Ab[row * 64 + (((kk * 4 + quad) ^ lx)) * 8];
            }
            #pragma unroll
            for (int jj = 0; jj < NJ; ++jj) {
                int row = wn * (NT / 4) + nq * (NT / 8) + jj * 16 + l15;
                #pragma unroll
                for (int kk = 0; kk < 2; ++kk)
                    bfr[jj][kk] = *(const bf16x8*)
                        &Bb[row * 64 + (((kk * 4 + quad) ^ lx)) * 8];
            }

            #pragma unroll
            for (int ii = 0; ii < 4; ++ii)
                #pragma unroll
                for (int jj = 0; jj < NJ; ++jj)
                    #pragma unroll
                    for (int kk = 0; kk < 2; ++kk)
                        acc[mq * 4 + ii][nq * NJ + jj] =
                            __builtin_amdgcn_mfma_f32_16x16x32_bf16(
                                af[ii][kk], bfr[jj][kk],
                                acc[mq * 4 + ii][nq * NJ + jj], 0, 0, 0);
        }
        __syncthreads();
    }

    // epilogue: C/D layout col=lane&15, row=quad*4+r
    #pragma unroll
    for (int i = 0; i < 8; ++i) {
        int rowb = m0 + wm * 128 + i * 16 + quad * 4;
        float bvr[4];
        if (rowBias) {
            #pragma unroll
            for (int r = 0; r < 4; ++r) bvr[r] = bias[rowb + r];
        }
        #pragma unroll
        for (int jf = 0; jf < NT / 64; ++jf) {
            int col = n0 + wn * (NT / 4) + jf * 16 + l15;
            float bc = rowBias ? 0.f : bias[col];
            #pragma unroll
            for (int r = 0; r < 4; ++r) {
                float val = acc[i][jf][r] + (rowBias ? bvr[r] : bc);
                C[(size_t)(rowb + r) * D_MODEL + col] = (CT)val;
            }
        }
    }
    #undef STAGE_HALF
}

// ---------------------------------------------------------------------------
// Fused projection GEMM (R16-verified): 192 blocks x 512 thr, XCD-chunked.
// ---------------------------------------------------------------------------
__global__ __launch_bounds__(512, 2)
void k_gemm_proj(const bf16* __restrict__ cq, const bf16* __restrict__ ck,
                 const bf16* __restrict__ cv,
                 const bf16* __restrict__ cWq, const bf16* __restrict__ cWk,
                 const bf16* __restrict__ cWv,
                 const float* __restrict__ bq, const float* __restrict__ bk,
                 const float* __restrict__ bv,
                 bf16* __restrict__ qproj, bf16* __restrict__ kproj,
                 bf16* __restrict__ vt)
{
    extern __shared__ __align__(16) bf16 smem[];
    bf16* As0 = smem;            // 2 x 16384 elems
    bf16* Bs0 = smem + 32768;    // 2 x 16384 elems

    const int bid = blockIdx.x;
    const int tid = (bid & 7) * 24 + (bid >> 3);   // 0..191
    if (tid < 64) {
        gemm8_core<bf16, 256>(cq, cWq, bq, qproj,
                              (tid >> 2) * 256, (tid & 3) * 256, false, As0, Bs0);
    } else if (tid < 128) {
        int u = tid - 64;
        gemm8_core<bf16, 256>(ck, cWk, bk, kproj,
                              (u >> 2) * 256, (u & 3) * 256, false, As0, Bs0);
    } else {
        int v = tid - 128;
        int b = v >> 4, m = (v >> 2) & 3, n = v & 3;
        gemm8_core<bf16, 256>(cWv, cv + (size_t)b * W_N, bv,
                              vt + (size_t)b * W_N, m * 256, n * 256, true,
                              As0, Bs0);
    }
}

// O-projection: 128 blocks x 512 thr, 256x128 tiles (16 m x 8 n), XCD-chunked.
__global__ __launch_bounds__(512, 2)
void k_gemm_o(const bf16* __restrict__ A, const bf16* __restrict__ W,
              const float* __restrict__ bb, float* __restrict__ C)
{
    extern __shared__ __align__(16) bf16 smem[];
    bf16* As0 = smem;            // 2 x 16384 elems
    bf16* Bs0 = smem + 32768;    // 2 x 8192 elems

    const int bid = blockIdx.x;
    const int tid = (bid & 7) * 16 + (bid >> 3);   // 0..127
    gemm8_core<float, 128>(A, W, bb, C, (tid >> 3) * 256, (tid & 7) * 128,
                           false, As0, Bs0);
}

// ---------------------------------------------------------------------------
// Flash attention, QBLK=128 (R17). Grid (B*H=64, L/128=8) = 512 blocks,
// 256 thr (4 waves); wave owns 32 q-rows = 2 groups g of 16. Per 64-s tile:
// prefetch K/V(t+1) -> QK^T 16 MFMA (kf shared across g) -> softmax 32 exp2
// + P-store into PADDED Past -> wave_barrier -> pf/accl/PV 20 MFMA (vf
// shared) -> __syncthreads. Past layout (bytes, per wave 6400):
// g*3200 + kk*1600 + sq*400 + qhi*160 + qlo*16 + e*2 with sq=(s>>3)&3,
// qhi=q>>3, qlo=q&7, e=s&7. 400/4=4, 160/4=8 mod 32 -> store bank =
// 16(quad&1)+8(quad>>1)+4(l15>>3)+4r+(e>>1): 32 distinct banks, worst
// 2-way (free). pf read = contiguous 16B, 16B-aligned, 2-way. LDS:
// Kst 16K + Vst 16K + Qst 16K + Past 25.6K = 73.6KB -> 2 blocks/CU.
// ---------------------------------------------------------------------------
__global__ __launch_bounds__(256)
void k_attn(const bf16* __restrict__ qproj, const bf16* __restrict__ kproj,
            const bf16* __restrict__ vt, const float* __restrict__ mbias_g,
            bf16* __restrict__ ctx)
{
    __shared__ alignas(16) bf16 Kst[2][4096];  // [f=j*2+kk][lane]*8, frag order
    __shared__ alignas(16) bf16 Vst[2][4096];
    __shared__ alignas(16) bf16 Qst[8192];     // 128q x 64d, frag order
    __shared__ alignas(16) bf16 Past[12800];   // padded P, per-wave 3200 elems

    const int t    = threadIdx.x;
    const int lane = t & 63;
    const int w    = t >> 6;
    const int l15  = lane & 15;
    const int quad = lane >> 4;

    const int b  = blockIdx.x >> 4;
    const int h  = blockIdx.x & 15;
    const int q0 = blockIdx.y * 128;

    // stage Q (4 frags per wave: g x kk)
    #pragma unroll
    for (int g = 0; g < 2; ++g)
        #pragma unroll
        for (int kk = 0; kk < 2; ++kk) {
            const bf16* gp = qproj
                + (size_t)(b * SEQ + q0 + w * 32 + g * 16 + l15) * D_MODEL
                + h * HDIM + kk * 32 + quad * 8;
            GLD(gp, Qst + (w * 4 + g * 2 + kk) * 512);
        }
    // stage K/V tile 0 into buffer 0
    #pragma unroll
    for (int i = 0; i < 2; ++i) {
        int f   = w * 2 + i;
        int row = (f >> 1) * 16 + l15;          // s-row (K) / d-row (Vt)
        int cb  = (f & 1) * 32 + quad * 8;
        GLD(kproj + (size_t)(b * SEQ + row) * D_MODEL + h * HDIM + cb,
            Kst[0] + f * 512);
        GLD(vt + (size_t)(b * 1024 + h * HDIM + row) * D_MODEL + cb,
            Vst[0] + f * 512);
    }
    __syncthreads();

    bf16x8 qf[2][2];
    #pragma unroll
    for (int g = 0; g < 2; ++g)
        #pragma unroll
        for (int kk = 0; kk < 2; ++kk)
            qf[g][kk] = *(const bf16x8*)&Qst[(w * 4 + g * 2 + kk) * 512 + lane * 8];

    bf16x8 ones;
    #pragma unroll
    for (int e = 0; e < 8; ++e) ones[e] = (bf16)1.0f;

    floatx4 o[2][4] = {};
    floatx4 accl[2] = {};

    // Past bases (elem units; all strides even in bytes)
    const int wrb = w * 3200 + (l15 >> 3) * 200 + (quad >> 1) * 80
                  + (quad & 1) * 32 + (l15 & 7);          // + g*1600 + (j>>1)*800 + (j&1)*400 + r*8
    const int prb = w * 3200 + quad * 200 + (l15 >> 3) * 80
                  + (l15 & 7) * 8;                        // + g*1600 + kk*800
    const float* __restrict__ mbb = mbias_g + b * SEQ;

    int cur = 0;
    for (int s0 = 0; s0 < SEQ; s0 += 64) {
        // prefetch next K/V tile into the other buffer BEFORE compute
        if (s0 + 64 < SEQ) {
            #pragma unroll
            for (int i = 0; i < 2; ++i) {
                int f   = w * 2 + i;
                int row = (f >> 1) * 16 + l15;
                int cb  = (f & 1) * 32 + quad * 8;
                GLD(kproj + (size_t)(b * SEQ + s0 + 64 + row) * D_MODEL
                        + h * HDIM + cb,
                    Kst[cur ^ 1] + f * 512);
                GLD(vt + (size_t)(b * 1024 + h * HDIM + row) * D_MODEL
                        + s0 + 64 + cb,
                    Vst[cur ^ 1] + f * 512);
            }
        }

        floatx4 s_acc[2][4] = {};
        #pragma unroll
        for (int j = 0; j < 4; ++j) {
            bf16x8 kf0 = *(const bf16x8*)&Kst[cur][(j * 2 + 0) * 512 + lane * 8];
            bf16x8 kf1 = *(const bf16x8*)&Kst[cur][(j * 2 + 1) * 512 + lane * 8];
            #pragma unroll
            for (int g = 0; g < 2; ++g) {
                s_acc[g][j] = __builtin_amdgcn_mfma_f32_16x16x32_bf16(
                    qf[g][0], kf0, s_acc[g][j], 0, 0, 0);
                s_acc[g][j] = __builtin_amdgcn_mfma_f32_16x16x32_bf16(
                    qf[g][1], kf1, s_acc[g][j], 0, 0, 0);
            }
        }

        #pragma unroll
        for (int j = 0; j < 4; ++j) {
            float mb = mbb[s0 + j * 16 + l15];
            #pragma unroll
            for (int g = 0; g < 2; ++g)
                #pragma unroll
                for (int r = 0; r < 4; ++r) {
                    float p = __builtin_amdgcn_exp2f(
                        fmaf(s_acc[g][j][r], SC2, mb));
                    Past[wrb + g * 1600 + (j >> 1) * 800 + (j & 1) * 400
                         + r * 8] = (bf16)p;
                }
        }
        __builtin_amdgcn_wave_barrier();

        bf16x8 pf[2][2];
        #pragma unroll
        for (int g = 0; g < 2; ++g)
            #pragma unroll
            for (int kk = 0; kk < 2; ++kk)
                pf[g][kk] = *(const bf16x8*)&Past[prb + g * 1600 + kk * 800];

        #pragma unroll
        for (int g = 0; g < 2; ++g)
            #pragma unroll
            for (int kk = 0; kk < 2; ++kk)
                accl[g] = __builtin_amdgcn_mfma_f32_16x16x32_bf16(
                    pf[g][kk], ones, accl[g], 0, 0, 0);

        #pragma unroll
        for (int j = 0; j < 4; ++j) {
            bf16x8 vf0 = *(const bf16x8*)&Vst[cur][(j * 2 + 0) * 512 + lane * 8];
            bf16x8 vf1 = *(const bf16x8*)&Vst[cur][(j * 2 + 1) * 512 + lane * 8];
            #pragma unroll
            for (int g = 0; g < 2; ++g) {
                o[g][j] = __builtin_amdgcn_mfma_f32_16x16x32_bf16(
                    pf[g][0], vf0, o[g][j], 0, 0, 0);
                o[g][j] = __builtin_amdgcn_mfma_f32_16x16x32_bf16(
                    pf[g][1], vf1, o[g][j], 0, 0, 0);
            }
        }

        __syncthreads();   // next K/V tile landed; buffers swap
        cur ^= 1;
    }

    #pragma unroll
    for (int g = 0; g < 2; ++g) {
        float inv[4];
        #pragma unroll
        for (int r = 0; r < 4; ++r)
            inv[r] = (accl[g][r] > 0.f) ? 1.f / accl[g][r] : 0.f;
        #pragma unroll
        for (int j = 0; j < 4; ++j)
            #pragma unroll
            for (int r = 0; r < 4; ++r) {
                int row = q0 + w * 32 + g * 16 + quad * 4 + r;
                int col = h * HDIM + j * 16 + l15;
                ctx[(size_t)(b * SEQ + row) * D_MODEL + col] =
                    (bf16)(o[g][j][r] * inv[r]);
            }
    }
}

// ---------------------------------------------------------------------------
extern "C" void kernel_launch(void* const* d_in, const int* in_sizes, int n_in,
                              void* d_out, int out_size, void* d_ws, size_t ws_size,
                              hipStream_t stream)
{
    // ws: [0,16K) mbias fp32 | [64K,+32MB) converted bf16 (q,k,v,Wq,Wk,Wv,Wo)
    //     | qproj 8MB | kproj 8MB | vt 8MB | ctx 8MB.   Total ~64.1MB.
    char* wsb = (char*)d_ws;
    float* mbias = (float*)wsb;
    bf16* cbase = (bf16*)(wsb + 65536);
    bf16 *cq = cbase, *ck = cq + ACT_N, *cv = ck + ACT_N;
    bf16 *cWq = cv + ACT_N, *cWk = cWq + W_N, *cWv = cWk + W_N, *cWo = cWv + W_N;
    bf16* qproj = cWo + W_N;
    bf16* kproj = qproj + ACT_N;
    bf16* vt    = kproj + ACT_N;
    bf16* ctx   = vt + ACT_N;
    float* out  = (float*)d_out;

    // allow big dynamic LDS on the 8-wave GEMMs (host-side, capture-safe)
    static bool attrset = false;
    if (!attrset) {
        hipFuncSetAttribute((const void*)k_gemm_proj,
                            hipFuncAttributeMaxDynamicSharedMemorySize, 131072);
        hipFuncSetAttribute((const void*)k_gemm_o,
                            hipFuncAttributeMaxDynamicSharedMemorySize, 131072);
        attrset = true;
    }

    k_convert_all<<<8193, 256, 0, stream>>>(
        (const float*)d_in[0], (const float*)d_in[1], (const float*)d_in[2],
        (const float*)d_in[4], (const float*)d_in[6], (const float*)d_in[8],
        (const float*)d_in[10], cbase, (const unsigned*)d_in[3], mbias);

    k_gemm_proj<<<192, 512, 131072, stream>>>(cq, ck, cv, cWq, cWk, cWv,
                                              (const float*)d_in[5],
                                              (const float*)d_in[7],
                                              (const float*)d_in[9],
                                              qproj, kproj, vt);
    k_attn<<<dim3(64, 8), 256, 0, stream>>>(qproj, kproj, vt, mbias, ctx);
    k_gemm_o<<<128, 512, 98304, stream>>>(ctx, cWo, (const float*)d_in[11], out);
}